// Round 1
// baseline (21213.499 us; speedup 1.0000x reference)
//
#include <hip/hip_runtime.h>
#include <hip/hip_bf16.h>
#include <math.h>

#define T_STEPS 256
#define B_SZ    256
#define I_SZ    128
#define N_SZ    1024
#define O_SZ    64
#define M_SZ    512   /* 2*B: x rows 0..255, y rows 256..511 */

#define H_STEP  0.05f
#define OMEGA   6.283185307179586f
#define GAMMA_C 0.1f
#define GR      0.03125f   /* 1/sqrt(1024) */
#define LAM_C   1.0f

typedef __attribute__((ext_vector_type(8))) short  short8;
typedef __attribute__((ext_vector_type(4))) short  short4v;
typedef __attribute__((ext_vector_type(4))) float  f32x4;

__device__ __forceinline__ float bf2f(unsigned short b) {
    union { unsigned int u; float f; } v; v.u = ((unsigned int)b) << 16; return v.f;
}
__device__ __forceinline__ unsigned short f2bf(float f) {
    union { float f; unsigned int u; } v; v.f = f;
    unsigned int r = v.u + 0x7fffu + ((v.u >> 16) & 1u);
    return (unsigned short)(r >> 16);
}

// ---------------------------------------------------------------------------
// Substep kernel: C = probe @ W_hh^T via 3-term bf16-split MFMA, fused RK4
// epilogue. Block tile 32(M) x 64(N), BK=32, 256 threads = 4 waves.
// Wave w: rows 16*(w&1).., cols 32*(w>>1).., 1x2 fragments of 16x16x32.
// ---------------------------------------------------------------------------
template<int S>
__global__ __launch_bounds__(256) void k_substep(
    const unsigned short* __restrict__ pInH, const unsigned short* __restrict__ pInL,
    const unsigned short* __restrict__ Wh,   const unsigned short* __restrict__ Wl,
    float* __restrict__ carry, float* __restrict__ accb,
    unsigned short* __restrict__ pOutH, unsigned short* __restrict__ pOutL,
    const float* __restrict__ bhh, const float* __restrict__ forcing, int fstride)
{
    // LDS tiles, padded row stride 40 elems (80B, multiple of 16B -> aligned b128)
    __shared__ __align__(16) unsigned short Ah[32 * 40];
    __shared__ __align__(16) unsigned short Al[32 * 40];
    __shared__ __align__(16) unsigned short Bh[64 * 40];
    __shared__ __align__(16) unsigned short Bl[64 * 40];

    const int tid  = threadIdx.x;
    const int bm   = blockIdx.x;      // 16 tiles of 32 rows
    const int bn   = blockIdx.y;      // 16 tiles of 64 cols
    const int lane = tid & 63;
    const int w    = tid >> 6;
    const int WR   = 16 * (w & 1);
    const int WC   = 32 * (w >> 1);
    const int kg   = lane >> 4;       // k-group 0..3
    const int lr   = lane & 15;

    // staging indices
    const int ar  = tid >> 3;             // A row 0..31, 8B/thread/buffer
    const int akc = (tid & 7) * 4;        // A k-col
    const int wr  = tid >> 2;             // W row 0..63, 16B/thread/buffer
    const int wkc = (tid & 3) * 8;        // W k-col
    const int aoff = (bm * 32 + ar) * N_SZ + akc;
    const int woff = (bn * 64 + wr) * N_SZ + wkc;

    f32x4 acc0 = {0.f, 0.f, 0.f, 0.f};
    f32x4 acc1 = {0.f, 0.f, 0.f, 0.f};

    for (int it = 0; it < 32; ++it) {
        const int k0 = it * 32;
        __syncthreads();
        *(short4v*)&Ah[ar * 40 + akc] = *(const short4v*)(pInH + aoff + k0);
        *(short4v*)&Al[ar * 40 + akc] = *(const short4v*)(pInL + aoff + k0);
        *(short8*) &Bh[wr * 40 + wkc] = *(const short8*) (Wh + woff + k0);
        *(short8*) &Bl[wr * 40 + wkc] = *(const short8*) (Wl + woff + k0);
        __syncthreads();

        short8 a_h  = *(const short8*)&Ah[(WR + lr) * 40 + kg * 8];
        short8 a_l  = *(const short8*)&Al[(WR + lr) * 40 + kg * 8];
        short8 b_h0 = *(const short8*)&Bh[(WC + lr) * 40 + kg * 8];
        short8 b_l0 = *(const short8*)&Bl[(WC + lr) * 40 + kg * 8];
        short8 b_h1 = *(const short8*)&Bh[(WC + 16 + lr) * 40 + kg * 8];
        short8 b_l1 = *(const short8*)&Bl[(WC + 16 + lr) * 40 + kg * 8];

        acc0 = __builtin_amdgcn_mfma_f32_16x16x32_bf16(a_h, b_h0, acc0, 0, 0, 0);
        acc1 = __builtin_amdgcn_mfma_f32_16x16x32_bf16(a_h, b_h1, acc1, 0, 0, 0);
        acc0 = __builtin_amdgcn_mfma_f32_16x16x32_bf16(a_h, b_l0, acc0, 0, 0, 0);
        acc1 = __builtin_amdgcn_mfma_f32_16x16x32_bf16(a_h, b_l1, acc1, 0, 0, 0);
        acc0 = __builtin_amdgcn_mfma_f32_16x16x32_bf16(a_l, b_h0, acc0, 0, 0, 0);
        acc1 = __builtin_amdgcn_mfma_f32_16x16x32_bf16(a_l, b_h1, acc1, 0, 0, 0);
    }

    // ---- fused RK4 epilogue ----
    #pragma unroll
    for (int fj = 0; fj < 2; ++fj) {
        f32x4 acc = fj ? acc1 : acc0;
        #pragma unroll
        for (int r = 0; r < 4; ++r) {
            const int m = bm * 32 + WR + kg * 4 + r;       // C/D row (m89 layout)
            const int n = bn * 64 + WC + fj * 16 + lr;     // C/D col
            const int idx  = m * N_SZ + n;
            const int pidx = (m ^ 256) * N_SZ + n;         // partner half

            const float base = carry[idx];
            float own, oth;
            if (S == 0) { own = base; oth = carry[pidx]; } // probe == carry exactly
            else {
                own = bf2f(pInH[idx])  + bf2f(pInL[idx]);
                oth = bf2f(pInH[pidx]) + bf2f(pInL[pidx]);
            }
            const float mm  = acc[r];
            const float rec = GR * (mm + bhh[n]);
            float k;
            if (m < 256) { // x half
                const float xp = own, yp = oth;
                const float r2 = xp * xp + yp * yp;
                k = (LAM_C - r2) * xp - OMEGA * yp + rec
                    + forcing[m * fstride + n] - GAMMA_C * xp;
            } else {       // y half
                const float yp = own, xp = oth;
                const float r2 = xp * xp + yp * yp;
                k = (LAM_C - r2) * yp + OMEGA * xp + rec - GAMMA_C * yp;
            }

            if (S == 0)      accb[idx] = k;
            else if (S < 3)  accb[idx] += 2.0f * k;

            float v;
            if (S < 3) {
                const float cn = (S == 2) ? H_STEP : 0.5f * H_STEP;
                v = base + cn * k;                  // next RK4 probe
            } else {
                v = base + (H_STEP / 6.0f) * (accb[idx] + k);  // new carry
                carry[idx] = v;
            }
            const unsigned short h = f2bf(v);
            pOutH[idx] = h;
            pOutL[idx] = f2bf(v - bf2f(h));
        }
    }
}

// ---------------------------------------------------------------------------
__global__ __launch_bounds__(256) void k_splitW(
    const float* __restrict__ W, unsigned short* __restrict__ Wh,
    unsigned short* __restrict__ Wl)
{
    const int i = (blockIdx.x * 256 + threadIdx.x) * 4;
    const float4 v = *(const float4*)(W + i);
    const float a[4] = {v.x, v.y, v.z, v.w};
    short4v h, l;
    #pragma unroll
    for (int j = 0; j < 4; ++j) {
        const unsigned short hb = f2bf(a[j]);
        h[j] = (short)hb;
        l[j] = (short)f2bf(a[j] - bf2f(hb));
    }
    *(short4v*)(Wh + i) = h;
    *(short4v*)(Wl + i) = l;
}

__global__ __launch_bounds__(256) void k_fc0(
    const float* __restrict__ batch0, const float* __restrict__ Wih,
    const float* __restrict__ bih, float* __restrict__ fc0)
{
    __shared__ float xr[I_SZ];
    const int b = blockIdx.x, tid = threadIdx.x;
    if (tid < I_SZ) xr[tid] = batch0[b * I_SZ + tid];
    __syncthreads();
    #pragma unroll
    for (int j = 0; j < 4; ++j) {
        const int n = tid + 256 * j;
        float s = bih[n];
        const float* wrow = Wih + n * I_SZ;
        for (int k = 0; k < I_SZ; ++k) s += xr[k] * wrow[k];
        fc0[b * N_SZ + n] = tanhf(s);
    }
}

__global__ void k_fc1(const float* __restrict__ bih, float* __restrict__ fc1)
{
    const int i = blockIdx.x * 256 + threadIdx.x;
    if (i < N_SZ) fc1[i] = tanhf(bih[i]);
}

__global__ __launch_bounds__(256) void k_out(
    const float* __restrict__ carry, const float* __restrict__ Who,
    const float* __restrict__ bho, float* __restrict__ out)
{
    __shared__ float xr[N_SZ];
    __shared__ float red[256];
    const int b = blockIdx.x, tid = threadIdx.x;
    #pragma unroll
    for (int j = 0; j < 4; ++j) xr[tid + 256 * j] = carry[b * N_SZ + tid + 256 * j];
    __syncthreads();
    const int o = tid & 63, seg = tid >> 6;
    const float* wrow = Who + o * N_SZ + seg * 256;
    const float* xs = xr + seg * 256;
    float s = 0.f;
    for (int k = 0; k < 256; ++k) s += xs[k] * wrow[k];
    red[tid] = s;
    __syncthreads();
    if (tid < 64)
        out[b * O_SZ + tid] = red[tid] + red[tid + 64] + red[tid + 128]
                            + red[tid + 192] + bho[tid];
}

// ---------------------------------------------------------------------------
extern "C" void kernel_launch(void* const* d_in, const int* in_sizes, int n_in,
                              void* d_out, int out_size, void* d_ws, size_t ws_size,
                              hipStream_t stream)
{
    const float* batch = (const float*)d_in[0];   // (T,B,I)
    const float* Wih   = (const float*)d_in[1];   // (N,I)
    const float* bih   = (const float*)d_in[2];   // (N)
    const float* Whh   = (const float*)d_in[3];   // (N,N)
    const float* bhh   = (const float*)d_in[4];   // (N)
    const float* Who   = (const float*)d_in[5];   // (O,N)
    const float* bho   = (const float*)d_in[6];   // (O)
    float* out = (float*)d_out;

    char* ws = (char*)d_ws;
    const size_t MB1 = 1024 * 1024;
    float*          carry = (float*)(ws + 0 * MB1);           // 2 MB (512x1024 f32)
    float*          accb  = (float*)(ws + 2 * MB1);           // 2 MB
    unsigned short* pAh   = (unsigned short*)(ws + 4 * MB1);  // 1 MB (512x1024 bf16)
    unsigned short* pAl   = (unsigned short*)(ws + 5 * MB1);
    unsigned short* pBh   = (unsigned short*)(ws + 6 * MB1);
    unsigned short* pBl   = (unsigned short*)(ws + 7 * MB1);
    unsigned short* Wh    = (unsigned short*)(ws + 8 * MB1);  // 2 MB (1024x1024 bf16)
    unsigned short* Wl    = (unsigned short*)(ws + 10 * MB1);
    float*          fc0   = (float*)(ws + 12 * MB1);          // 1 MB (256x1024 f32)
    float*          fc1   = (float*)(ws + 13 * MB1);          // 4 KB

    const size_t MN = (size_t)M_SZ * N_SZ;
    hipMemsetAsync(carry, 0, MN * 4, stream);   // x0 = y0 = 0
    hipMemsetAsync(pAh,   0, MN * 2, stream);   // split(0) == 0
    hipMemsetAsync(pAl,   0, MN * 2, stream);

    k_splitW<<<(N_SZ * N_SZ) / (256 * 4), 256, 0, stream>>>(Whh, Wh, Wl);
    k_fc0<<<B_SZ, 256, 0, stream>>>(batch, Wih, bih, fc0);
    k_fc1<<<4, 256, 0, stream>>>(bih, fc1);

    const dim3 grid(16, 16);
    for (int t = 0; t < T_STEPS; ++t) {
        const float* f = (t == 0) ? fc0 : fc1;
        const int fs = (t == 0) ? N_SZ : 0;
        k_substep<0><<<grid, 256, 0, stream>>>(pAh, pAl, Wh, Wl, carry, accb, pBh, pBl, bhh, f, fs);
        k_substep<1><<<grid, 256, 0, stream>>>(pBh, pBl, Wh, Wl, carry, accb, pAh, pAl, bhh, f, fs);
        k_substep<2><<<grid, 256, 0, stream>>>(pAh, pAl, Wh, Wl, carry, accb, pBh, pBl, bhh, f, fs);
        k_substep<3><<<grid, 256, 0, stream>>>(pBh, pBl, Wh, Wl, carry, accb, pAh, pAl, bhh, f, fs);
    }
    k_out<<<B_SZ, 256, 0, stream>>>(carry, Who, bho, out);
}